// Round 6
// baseline (214.614 us; speedup 1.0000x reference)
//
#include <hip/hip_runtime.h>
#include <math.h>

#define EPS_F 1e-7f

constexpr int Bc = 32, Tc = 8192, Kc = 16;
constexpr int ROWS   = Bc * Tc;            // 262144
constexpr int BLOCK  = 256;
constexpr int NITEM4 = ROWS * 4;           // 1048576 vec4 items
constexpr int NBLK   = NITEM4 / BLOCK;     // 4096 blocks, 1 item/thread

typedef unsigned long long u64;

__device__ __forceinline__ u64 shflx64(u64 v, int m) {
  unsigned lo = __shfl_xor((unsigned)v, m, 64);
  unsigned hi = __shfl_xor((unsigned)(v >> 32), m, 64);
  return ((u64)hi << 32) | lo;
}

// Flat one-vec4-item-per-thread (R3's best-occupancy shape) with ALL 13
// loads issued up front and pinned there by sched_barrier(0) -- R3/R5 showed
// the machine scheduler otherwise sinks loads to just-before-use (VGPR 32/56)
// killing per-wave MLP. Unconditional wscore/oshw loads keep one basic block
// so nothing can be sunk across the branch. BCE uses the product trick
// (sum of masked -log x == -log of product): 8 logs/thread -> 2.
__global__ __launch_bounds__(BLOCK) void loss_main(
    const float* __restrict__ trig,
    const float* __restrict__ valp,
    const float* __restrict__ clog,
    const float* __restrict__ wscore,
    const int*   __restrict__ live,
    const int*   __restrict__ cid,
    const float* __restrict__ ofire,
    const int*   __restrict__ ocan,
    const float* __restrict__ ovalid,
    const float* __restrict__ oshw,
    const int*   __restrict__ ocid,
    float* __restrict__ part)            // [NBLK][6]
{
  const int t    = blockIdx.x * BLOCK + threadIdx.x;   // vec4 item index
  const int lane = threadIdx.x & 63;
  const bool isRowLead = (t & 3) == 0;

  // ---- all loads up front, consumption order, single basic block
  const int4   oc = ((const int4*)  ocid)[t];
  const int4   cc = ((const int4*)  ocan)[t];
  const float4 ff = ((const float4*)ofire)[t];
  const float4 vv = ((const float4*)ovalid)[t];
  const int4   cd = ((const int4*)  cid)[t];
  const int4   lm = ((const int4*)  live)[t];
  const float4 ph = ((const float4*)trig)[t];
  const float4 pq = ((const float4*)valp)[t];
  const float4 lA = ((const float4*)clog)[t * 3 + 0];
  const float4 lB = ((const float4*)clog)[t * 3 + 1];
  const float4 lC = ((const float4*)clog)[t * 3 + 2];
  const float  wx = wscore[t >> 2];   // 4 lanes share a row: L1 broadcast
  const float  wy = oshw[t >> 2];
  __builtin_amdgcn_sched_barrier(0);  // loads may not sink past this point

  // ---- per-lane partial oracle table (my 4 slots, slot order)
  u64 tblLo = 0ull, tblHi = 0ull, fndLo = 0ull, fndHi = 0ull;
  {
    const int   ocs[4] = {oc.x, oc.y, oc.z, oc.w};
    const int   ccs[4] = {cc.x, cc.y, cc.z, cc.w};
    const float ffs[4] = {ff.x, ff.y, ff.z, ff.w};
    const float vvs[4] = {vv.x, vv.y, vv.z, vv.w};
    #pragma unroll
    for (int j = 0; j < 4; ++j) {
      const unsigned c  = (unsigned)ocs[j] & 31u;
      const unsigned sh = (c & 15u) * 4u;
      const bool isLo   = c < 16u;
      const bool seen   = (((isLo ? fndLo : fndHi) >> sh) & 1ull) != 0ull;
      const unsigned nib = (unsigned)ffs[j] | ((unsigned)vvs[j] << 1) |
                           ((unsigned)ccs[j] << 2);
      const u64 add  = seen ? 0ull : ((u64)nib << sh);
      const u64 fadd = 0xFull << sh;
      tblLo |= isLo ? add : 0ull;
      tblHi |= isLo ? 0ull : add;
      fndLo |= isLo ? fadd : 0ull;
      fndHi |= isLo ? 0ull : fadd;
    }
  }

  // ---- merge across the 4-lane row group (lower lane = earlier slot wins)
  #pragma unroll
  for (int m = 1; m <= 2; m <<= 1) {
    const u64 pTL = shflx64(tblLo, m);
    const u64 pTH = shflx64(tblHi, m);
    const u64 pFL = shflx64(fndLo, m);
    const u64 pFH = shflx64(fndHi, m);
    const bool iLow = (lane & m) == 0;
    const u64 loTL = iLow ? tblLo : pTL, hiTL = iLow ? pTL : tblLo;
    const u64 loTH = iLow ? tblHi : pTH, hiTH = iLow ? pTH : tblHi;
    const u64 loFL = iLow ? fndLo : pFL, hiFL = iLow ? pFL : fndLo;
    const u64 loFH = iLow ? fndHi : pFH, hiFH = iLow ? pFH : fndHi;
    tblLo = loTL | (hiTL & ~loFL);
    tblHi = loTH | (hiTH & ~loFH);
    fndLo = loFL | hiFL;
    fndHi = loFH | hiFH;
  }

  // ---- losses for my 4 slots
  float s1 = 0.f, s2 = 0.f, s3 = 0.f;
  float prodF = 1.f, prodV = 1.f;
  {
    const int   cds[4] = {cd.x, cd.y, cd.z, cd.w};
    const int   lms[4] = {lm.x, lm.y, lm.z, lm.w};
    const float phs[4] = {ph.x, ph.y, ph.z, ph.w};
    const float pqs[4] = {pq.x, pq.y, pq.z, pq.w};
    const float L0[4] = {lA.x, lA.w, lB.z, lC.y};
    const float L1[4] = {lA.y, lB.x, lB.w, lC.z};
    const float L2[4] = {lA.z, lB.y, lC.x, lC.w};
    #pragma unroll
    for (int j = 0; j < 4; ++j) {
      const unsigned c  = (unsigned)cds[j] & 31u;
      const unsigned sh = (c & 15u) * 4u;
      const bool isLo   = c < 16u;
      const bool fnd = (c != 0u) &&
                       ((((isLo ? fndLo : fndHi) >> sh) & 1ull) != 0ull);
      unsigned nib = (unsigned)(((isLo ? tblLo : tblHi) >> sh)) & 15u;
      nib = fnd ? nib : 0u;
      const int can_t = (int)(nib >> 2);
      const bool mb   = lms[j] != 0;

      // BCE factors: x = (y ? p : 1-p), clamp p to [eps, 1-eps]; masked-out
      // slots contribute factor 1.0 (log contribution 0)
      const float p  = fminf(fmaxf(phs[j], EPS_F), 1.f - EPS_F);
      const float xf = (nib & 1u) ? p : 1.f - p;
      prodF *= mb ? xf : 1.f;
      const float q  = fminf(fmaxf(pqs[j], EPS_F), 1.f - EPS_F);
      const float xv = (nib & 2u) ? q : 1.f - q;
      prodV *= mb ? xv : 1.f;

      // cancel CE; logits ~ N(0,1) so unshifted LSE cannot overflow
      const float has = (can_t > 0 && mb) ? 1.f : 0.f;
      const int tgt = (can_t - 1) < 0 ? 0 : (can_t - 1);
      const float l0 = L0[j], l1 = L1[j], l2 = L2[j];
      const float lse = __logf(__expf(l0) + __expf(l1) + __expf(l2));
      const float lt  = (tgt == 0) ? l0 : ((tgt == 1) ? l1 : l2);

      s1 += mb ? 1.f : 0.f;
      s2 += (lse - lt) * has;
      s3 += has;
    }
  }
  const float s0 = -__logf(prodF);
  const float s4 = -__logf(prodV);

  // ---- write term (one lane per row)
  float s5 = 0.f;
  if (isRowLead) {
    s5 = fmaxf(wx, 0.f) - wx * wy + __logf(1.f + __expf(-fabsf(wx)));
  }

  // ---- wave reduce, then block reduce via LDS
  float v[6] = {s0, s1, s2, s3, s4, s5};
  #pragma unroll
  for (int off = 32; off > 0; off >>= 1) {
    #pragma unroll
    for (int i = 0; i < 6; ++i) v[i] += __shfl_down(v[i], off, 64);
  }
  __shared__ float red[4][6];
  const int w = threadIdx.x >> 6;
  if (lane == 0) {
    #pragma unroll
    for (int i = 0; i < 6; ++i) red[w][i] = v[i];
  }
  __syncthreads();
  if (threadIdx.x == 0) {
    #pragma unroll
    for (int i = 0; i < 6; ++i)
      part[blockIdx.x * 6 + i] = red[0][i] + red[1][i] + red[2][i] + red[3][i];
  }
}

// Reduce NBLK partials in double, compute the 5 outputs.
__global__ __launch_bounds__(BLOCK) void loss_finalize(
    const float* __restrict__ part, float* __restrict__ out)
{
  double v[6] = {0, 0, 0, 0, 0, 0};
  for (int r = threadIdx.x; r < NBLK; r += BLOCK) {
    #pragma unroll
    for (int i = 0; i < 6; ++i) v[i] += (double)part[r * 6 + i];
  }
  #pragma unroll
  for (int off = 32; off > 0; off >>= 1) {
    #pragma unroll
    for (int i = 0; i < 6; ++i) v[i] += __shfl_down(v[i], off, 64);
  }
  __shared__ double red[4][6];
  const int w = threadIdx.x >> 6, lane = threadIdx.x & 63;
  if (lane == 0) {
    #pragma unroll
    for (int i = 0; i < 6; ++i) red[w][i] = v[i];
  }
  __syncthreads();
  if (threadIdx.x == 0) {
    double a[6];
    #pragma unroll
    for (int i = 0; i < 6; ++i) a[i] = red[0][i] + red[1][i] + red[2][i] + red[3][i];
    const double live_n = a[1] < 1.0 ? 1.0 : a[1];
    const double fire   = a[0] / live_n;                                   // LAM_FIRE   = 1.0
    const double cancel = (a[3] > 0.0) ? a[2] / (a[3] < 1.0 ? 1.0 : a[3])  // LAM_CANCEL = 1.0
                                       : 0.0;
    const double valid  = 0.5 * a[4] / live_n;                             // LAM_VALID  = 0.5
    const double wr     = 0.5 * a[5] / (double)ROWS;                       // LAM_WRITE  = 0.5
    out[0] = (float)fire;
    out[1] = (float)cancel;
    out[2] = (float)valid;
    out[3] = (float)wr;
    out[4] = (float)(fire + cancel + valid + wr);
  }
}

extern "C" void kernel_launch(void* const* d_in, const int* in_sizes, int n_in,
                              void* d_out, int out_size, void* d_ws, size_t ws_size,
                              hipStream_t stream) {
  const float* trig   = (const float*)d_in[0];
  const float* valp   = (const float*)d_in[1];
  const float* clog   = (const float*)d_in[2];
  const float* wscore = (const float*)d_in[3];
  const int*   live   = (const int*)  d_in[4];
  const int*   cid    = (const int*)  d_in[5];
  const float* ofire  = (const float*)d_in[6];
  const int*   ocan   = (const int*)  d_in[7];
  const float* ovalid = (const float*)d_in[8];
  const float* oshw   = (const float*)d_in[9];
  const int*   ocid   = (const int*)  d_in[10];
  float* out  = (float*)d_out;
  float* part = (float*)d_ws;   // NBLK*6 floats = 96 KB, fully overwritten

  loss_main<<<NBLK, BLOCK, 0, stream>>>(trig, valp, clog, wscore, live, cid,
                                        ofire, ocan, ovalid, oshw, ocid, part);
  loss_finalize<<<1, BLOCK, 0, stream>>>(part, out);
}

// Round 7
// 208.546 us; speedup vs baseline: 1.0291x; 1.0291x over previous
//
#include <hip/hip_runtime.h>
#include <math.h>

#define EPS_F 1e-7f

constexpr int Bc = 32, Tc = 8192, Kc = 16;
constexpr int ROWS   = Bc * Tc;            // 262144
constexpr int BLOCK  = 256;
constexpr int NITEM4 = ROWS * 4;           // 1048576 vec4 items
constexpr int NBLK   = NITEM4 / BLOCK;     // 4096 blocks, 1 vec4 item/thread
constexpr int ROWS_PER_BLK = BLOCK / 4;    // 64 rows per block

// LDS layout (bytes): 8 regions x 4KB for the 16B/item arrays, 12KB for
// cancel_logits (48B/item), then 2 x 256B for wscore/oshw rows.
constexpr int R_OCID = 0 * 4096;
constexpr int R_OCAN = 1 * 4096;
constexpr int R_OFIR = 2 * 4096;
constexpr int R_OVAL = 3 * 4096;
constexpr int R_CID  = 4 * 4096;
constexpr int R_LIVE = 5 * 4096;
constexpr int R_TRIG = 6 * 4096;
constexpr int R_VALP = 7 * 4096;
constexpr int R_CLOG = 8 * 4096;           // 12 KB
constexpr int R_WSC  = R_CLOG + 12288;     // 256 B
constexpr int R_OSW  = R_WSC + 256;        // 256 B
constexpr int SMEM_BYTES = R_OSW + 256;    // 45568 B -> 3 blocks/CU

typedef unsigned long long u64;

__device__ __forceinline__ u64 shflx64(u64 v, int m) {
  unsigned lo = __shfl_xor((unsigned)v, m, 64);
  unsigned hi = __shfl_xor((unsigned)(v >> 32), m, 64);
  return ((u64)hi << 32) | lo;
}

// Async global->LDS DMA. LDS dest is WAVE-UNIFORM base; HW scatters lane i's
// data to base + i*size [m104/m108]. No destination VGPRs -> the register
// allocator cannot serialize the burst (the R3-R6 failure mode).
__device__ __forceinline__ void dma16(void* lds, const void* g) {
  __builtin_amdgcn_global_load_lds(
      (const __attribute__((address_space(1))) void*)g,
      (__attribute__((address_space(3))) void*)lds, 16, 0, 0);
}
__device__ __forceinline__ void dma4(void* lds, const void* g) {
  __builtin_amdgcn_global_load_lds(
      (const __attribute__((address_space(1))) void*)g,
      (__attribute__((address_space(3))) void*)lds, 4, 0, 0);
}

__global__ __launch_bounds__(BLOCK) void loss_main(
    const float* __restrict__ trig,
    const float* __restrict__ valp,
    const float* __restrict__ clog,
    const float* __restrict__ wscore,
    const int*   __restrict__ live,
    const int*   __restrict__ cid,
    const float* __restrict__ ofire,
    const int*   __restrict__ ocan,
    const float* __restrict__ ovalid,
    const float* __restrict__ oshw,
    const int*   __restrict__ ocid,
    float* __restrict__ part)            // [NBLK][6]
{
  __shared__ __align__(16) char smem[SMEM_BYTES];

  const int tid  = threadIdx.x;
  const int lane = tid & 63;
  const int w    = tid >> 6;                       // wave id 0..3
  const int t0   = blockIdx.x * BLOCK;             // first vec4 item of tile
  const int gi   = t0 + w * 64 + lane;             // my vec4 item (== t0+tid)

  // ---- stage the whole tile: 11 x 1KB DMAs per wave + row scalars.
  // LDS base per DMA is wave-uniform (w is uniform); global addr is per-lane.
  {
    char* sb = smem + w * 1024;
    const size_t o16 = (size_t)gi * 16;
    dma16(sb + R_OCID, (const char*)ocid  + o16);
    dma16(sb + R_OCAN, (const char*)ocan  + o16);
    dma16(sb + R_OFIR, (const char*)ofire + o16);
    dma16(sb + R_OVAL, (const char*)ovalid+ o16);
    dma16(sb + R_CID,  (const char*)cid   + o16);
    dma16(sb + R_LIVE, (const char*)live  + o16);
    dma16(sb + R_TRIG, (const char*)trig  + o16);
    dma16(sb + R_VALP, (const char*)valp  + o16);
    // clog: wave's 3KB chunk staged as 3 contiguous 1KB DMAs
    const char* gc = (const char*)clog + (size_t)(t0 + w * 64) * 48;
    char* sc = smem + R_CLOG + w * 3072;
    dma16(sc + 0,    gc + 0    + lane * 16);
    dma16(sc + 1024, gc + 1024 + lane * 16);
    dma16(sc + 2048, gc + 2048 + lane * 16);
    // row scalars: wave 0 -> wscore, wave 1 -> oshw (64 rows x 4B each)
    const int r0 = blockIdx.x * ROWS_PER_BLK;
    if (w == 0)      dma4(smem + R_WSC, (const char*)wscore + (size_t)(r0 + lane) * 4);
    else if (w == 1) dma4(smem + R_OSW, (const char*)oshw   + (size_t)(r0 + lane) * 4);
  }
  __syncthreads();   // drains vmcnt(0): all DMAs landed

  // ---- read my fragments back from LDS (stride-16 = free 2-way aliasing)
  const int4   oc = *(const int4*)  (smem + R_OCID + tid * 16);
  const int4   cc = *(const int4*)  (smem + R_OCAN + tid * 16);
  const float4 ff = *(const float4*)(smem + R_OFIR + tid * 16);
  const float4 vv = *(const float4*)(smem + R_OVAL + tid * 16);
  const int4   cd = *(const int4*)  (smem + R_CID  + tid * 16);
  const int4   lm = *(const int4*)  (smem + R_LIVE + tid * 16);
  const float4 ph = *(const float4*)(smem + R_TRIG + tid * 16);
  const float4 pq = *(const float4*)(smem + R_VALP + tid * 16);
  const float4 lA = *(const float4*)(smem + R_CLOG + tid * 48 + 0);
  const float4 lB = *(const float4*)(smem + R_CLOG + tid * 48 + 16);
  const float4 lC = *(const float4*)(smem + R_CLOG + tid * 48 + 32);
  const float  wx = *(const float*) (smem + R_WSC + (tid >> 2) * 4);
  const float  wy = *(const float*) (smem + R_OSW + (tid >> 2) * 4);

  // ---- per-lane partial oracle table (my 4 slots, slot order)
  u64 tblLo = 0ull, tblHi = 0ull, fndLo = 0ull, fndHi = 0ull;
  {
    const int   ocs[4] = {oc.x, oc.y, oc.z, oc.w};
    const int   ccs[4] = {cc.x, cc.y, cc.z, cc.w};
    const float ffs[4] = {ff.x, ff.y, ff.z, ff.w};
    const float vvs[4] = {vv.x, vv.y, vv.z, vv.w};
    #pragma unroll
    for (int j = 0; j < 4; ++j) {
      const unsigned c  = (unsigned)ocs[j] & 31u;
      const unsigned sh = (c & 15u) * 4u;
      const bool isLo   = c < 16u;
      const bool seen   = (((isLo ? fndLo : fndHi) >> sh) & 1ull) != 0ull;
      const unsigned nib = (unsigned)ffs[j] | ((unsigned)vvs[j] << 1) |
                           ((unsigned)ccs[j] << 2);
      const u64 add  = seen ? 0ull : ((u64)nib << sh);
      const u64 fadd = 0xFull << sh;
      tblLo |= isLo ? add : 0ull;
      tblHi |= isLo ? 0ull : add;
      fndLo |= isLo ? fadd : 0ull;
      fndHi |= isLo ? 0ull : fadd;
    }
  }

  // ---- merge across the 4-lane row group (lower lane = earlier slot wins)
  #pragma unroll
  for (int m = 1; m <= 2; m <<= 1) {
    const u64 pTL = shflx64(tblLo, m);
    const u64 pTH = shflx64(tblHi, m);
    const u64 pFL = shflx64(fndLo, m);
    const u64 pFH = shflx64(fndHi, m);
    const bool iLow = (lane & m) == 0;
    const u64 loTL = iLow ? tblLo : pTL, hiTL = iLow ? pTL : tblLo;
    const u64 loTH = iLow ? tblHi : pTH, hiTH = iLow ? pTH : tblHi;
    const u64 loFL = iLow ? fndLo : pFL, hiFL = iLow ? pFL : fndLo;
    const u64 loFH = iLow ? fndHi : pFH, hiFH = iLow ? pFH : fndHi;
    tblLo = loTL | (hiTL & ~loFL);
    tblHi = loTH | (hiTH & ~loFH);
    fndLo = loFL | hiFL;
    fndHi = loFH | hiFH;
  }

  // ---- losses for my 4 slots (R3's proven compute path)
  float s0 = 0.f, s1 = 0.f, s2 = 0.f, s3 = 0.f, s4 = 0.f;
  {
    const int   cds[4] = {cd.x, cd.y, cd.z, cd.w};
    const int   lms[4] = {lm.x, lm.y, lm.z, lm.w};
    const float phs[4] = {ph.x, ph.y, ph.z, ph.w};
    const float pqs[4] = {pq.x, pq.y, pq.z, pq.w};
    const float L0[4] = {lA.x, lA.w, lB.z, lC.y};
    const float L1[4] = {lA.y, lB.x, lB.w, lC.z};
    const float L2[4] = {lA.z, lB.y, lC.x, lC.w};
    #pragma unroll
    for (int j = 0; j < 4; ++j) {
      const unsigned c  = (unsigned)cds[j] & 31u;
      const unsigned sh = (c & 15u) * 4u;
      const bool isLo   = c < 16u;
      const bool fnd = (c != 0u) &&
                       ((((isLo ? fndLo : fndHi) >> sh) & 1ull) != 0ull);
      unsigned nib = (unsigned)(((isLo ? tblLo : tblHi) >> sh)) & 15u;
      nib = fnd ? nib : 0u;
      const float fire_t = (float)(nib & 1u);
      const float val_t  = (float)((nib >> 1) & 1u);
      const int   can_t  = (int)(nib >> 2);

      const float m = lms[j] ? 1.f : 0.f;

      const float p  = fminf(fmaxf(phs[j], EPS_F), 1.f - EPS_F);
      const float bf = -__logf((fire_t != 0.f) ? p : 1.f - p);
      const float q  = fminf(fmaxf(pqs[j], EPS_F), 1.f - EPS_F);
      const float bv = -__logf((val_t != 0.f) ? q : 1.f - q);

      const float has = (can_t > 0 && lms[j]) ? 1.f : 0.f;
      const int tgt = (can_t - 1) < 0 ? 0 : (can_t - 1);
      const float l0 = L0[j], l1 = L1[j], l2 = L2[j];
      const float mx  = fmaxf(l0, fmaxf(l1, l2));
      const float lse = mx + __logf(__expf(l0 - mx) + __expf(l1 - mx) +
                                    __expf(l2 - mx));
      const float lt  = (tgt == 0) ? l0 : ((tgt == 1) ? l1 : l2);

      s0 += bf * m;
      s1 += m;
      s2 += (lse - lt) * has;
      s3 += has;
      s4 += bv * m;
    }
  }

  // ---- write term (one lane per row)
  float s5 = 0.f;
  if ((tid & 3) == 0) {
    s5 = fmaxf(wx, 0.f) - wx * wy + __logf(1.f + __expf(-fabsf(wx)));
  }

  // ---- wave reduce, then block reduce via LDS
  float v[6] = {s0, s1, s2, s3, s4, s5};
  #pragma unroll
  for (int off = 32; off > 0; off >>= 1) {
    #pragma unroll
    for (int i = 0; i < 6; ++i) v[i] += __shfl_down(v[i], off, 64);
  }
  __shared__ float red[4][6];
  if (lane == 0) {
    #pragma unroll
    for (int i = 0; i < 6; ++i) red[w][i] = v[i];
  }
  __syncthreads();
  if (tid == 0) {
    #pragma unroll
    for (int i = 0; i < 6; ++i)
      part[blockIdx.x * 6 + i] = red[0][i] + red[1][i] + red[2][i] + red[3][i];
  }
}

// Reduce NBLK partials in double, compute the 5 outputs.
__global__ __launch_bounds__(BLOCK) void loss_finalize(
    const float* __restrict__ part, float* __restrict__ out)
{
  double v[6] = {0, 0, 0, 0, 0, 0};
  for (int r = threadIdx.x; r < NBLK; r += BLOCK) {
    #pragma unroll
    for (int i = 0; i < 6; ++i) v[i] += (double)part[r * 6 + i];
  }
  #pragma unroll
  for (int off = 32; off > 0; off >>= 1) {
    #pragma unroll
    for (int i = 0; i < 6; ++i) v[i] += __shfl_down(v[i], off, 64);
  }
  __shared__ double red[4][6];
  const int w = threadIdx.x >> 6, lane = threadIdx.x & 63;
  if (lane == 0) {
    #pragma unroll
    for (int i = 0; i < 6; ++i) red[w][i] = v[i];
  }
  __syncthreads();
  if (threadIdx.x == 0) {
    double a[6];
    #pragma unroll
    for (int i = 0; i < 6; ++i) a[i] = red[0][i] + red[1][i] + red[2][i] + red[3][i];
    const double live_n = a[1] < 1.0 ? 1.0 : a[1];
    const double fire   = a[0] / live_n;                                   // LAM_FIRE   = 1.0
    const double cancel = (a[3] > 0.0) ? a[2] / (a[3] < 1.0 ? 1.0 : a[3])  // LAM_CANCEL = 1.0
                                       : 0.0;
    const double valid  = 0.5 * a[4] / live_n;                             // LAM_VALID  = 0.5
    const double wr     = 0.5 * a[5] / (double)ROWS;                       // LAM_WRITE  = 0.5
    out[0] = (float)fire;
    out[1] = (float)cancel;
    out[2] = (float)valid;
    out[3] = (float)wr;
    out[4] = (float)(fire + cancel + valid + wr);
  }
}

extern "C" void kernel_launch(void* const* d_in, const int* in_sizes, int n_in,
                              void* d_out, int out_size, void* d_ws, size_t ws_size,
                              hipStream_t stream) {
  const float* trig   = (const float*)d_in[0];
  const float* valp   = (const float*)d_in[1];
  const float* clog   = (const float*)d_in[2];
  const float* wscore = (const float*)d_in[3];
  const int*   live   = (const int*)  d_in[4];
  const int*   cid    = (const int*)  d_in[5];
  const float* ofire  = (const float*)d_in[6];
  const int*   ocan   = (const int*)  d_in[7];
  const float* ovalid = (const float*)d_in[8];
  const float* oshw   = (const float*)d_in[9];
  const int*   ocid   = (const int*)  d_in[10];
  float* out  = (float*)d_out;
  float* part = (float*)d_ws;   // NBLK*6 floats = 96 KB, fully overwritten

  loss_main<<<NBLK, BLOCK, 0, stream>>>(trig, valp, clog, wscore, live, cid,
                                        ofire, ocan, ovalid, oshw, ocid, part);
  loss_finalize<<<1, BLOCK, 0, stream>>>(part, out);
}